// Round 1
// baseline (15806.314 us; speedup 1.0000x reference)
//
#include <hip/hip_runtime.h>
#include <math.h>

// ---------------------------------------------------------------------------
// TransformerXL forward (fp32 baseline).
// QLEN=512 MEM_LEN=512 KLEN=1024 BSZ=4 NH=16 DH=64 DM=1024 DI=4096 V=32000 L=6
// ---------------------------------------------------------------------------

#define LINMOD (1 << 30)
constexpr int F_RELU = 1, F_SHIFT = 2, F_BNT = 4;

// Generic tiled GEMM: C[M,N] = A[M,K] * B^T (B is [N,K] row-major), or with
// F_BNT: B is [K,N] row-major. Batched via blockIdx.z with (mod, lo, hi)
// offset = (z%mod)*lo + (z/mod)*hi. F_SHIFT: TransformerXL rel-shift epilogue
// (C[row][col+row-(M-1)] += acc, accumulate into existing C).
__global__ __launch_bounds__(256)
void gemm_kernel(const float* __restrict__ A, int lda, long alo, long ahi, int amod,
                 const float* __restrict__ B, int ldb, long blo, long bhi, int bmod,
                 float* __restrict__ C, int ldc, long clo, long chi, int cmod,
                 const float* __restrict__ bias,
                 int M, int N, int K, int flags)
{
    __shared__ float As[8][128];
    __shared__ float Bs[8][128];
    const int z = blockIdx.z;
    A += (long)(z % amod) * alo + (long)(z / amod) * ahi;
    B += (long)(z % bmod) * blo + (long)(z / bmod) * bhi;
    C += (long)(z % cmod) * clo + (long)(z / cmod) * chi;

    const int m0 = blockIdx.y * 128, n0 = blockIdx.x * 128;
    const int t = threadIdx.x;
    const int tx = t & 15, ty = t >> 4;

    // A staging: thread loads float4 at (row am, k-offset ak)
    const int am = t >> 1, ak = (t & 1) * 4;
    const float* Ap = A + (long)(m0 + am) * lda + ak;
    const bool aok = (m0 + am) < M;

    const float* Bp;
    int bm, bk;
    bool bok;
    long stepB;
    if (flags & F_BNT) {
        bk = t >> 5; bm = (t & 31) * 4;            // row k, col n
        Bp = B + (long)bk * ldb + (n0 + bm);
        bok = (n0 + bm) < N;
        stepB = (long)8 * ldb;
    } else {
        bm = t >> 1; bk = (t & 1) * 4;             // row n, col k
        Bp = B + (long)(n0 + bm) * ldb + bk;
        bok = (n0 + bm) < N;
        stepB = 8;
    }

    float acc[8][8];
    #pragma unroll
    for (int r = 0; r < 8; ++r)
        #pragma unroll
        for (int c = 0; c < 8; ++c) acc[r][c] = 0.f;

    const int nk = K >> 3;   // K is always a multiple of 8 here
    for (int kt = 0; kt < nk; ++kt) {
        float4 av = make_float4(0.f, 0.f, 0.f, 0.f);
        float4 bv = make_float4(0.f, 0.f, 0.f, 0.f);
        if (aok) av = *(const float4*)Ap;
        if (bok) bv = *(const float4*)Bp;
        Ap += 8; Bp += stepB;
        __syncthreads();
        As[ak + 0][am] = av.x; As[ak + 1][am] = av.y;
        As[ak + 2][am] = av.z; As[ak + 3][am] = av.w;
        if (flags & F_BNT) {
            *(float4*)&Bs[bk][bm] = bv;
        } else {
            Bs[bk + 0][bm] = bv.x; Bs[bk + 1][bm] = bv.y;
            Bs[bk + 2][bm] = bv.z; Bs[bk + 3][bm] = bv.w;
        }
        __syncthreads();
        #pragma unroll
        for (int kk = 0; kk < 8; ++kk) {
            float4 a0 = *(const float4*)&As[kk][ty * 8];
            float4 a1 = *(const float4*)&As[kk][ty * 8 + 4];
            float4 b0 = *(const float4*)&Bs[kk][tx * 8];
            float4 b1 = *(const float4*)&Bs[kk][tx * 8 + 4];
            float ar[8] = {a0.x, a0.y, a0.z, a0.w, a1.x, a1.y, a1.z, a1.w};
            float br[8] = {b0.x, b0.y, b0.z, b0.w, b1.x, b1.y, b1.z, b1.w};
            #pragma unroll
            for (int r = 0; r < 8; ++r)
                #pragma unroll
                for (int c = 0; c < 8; ++c)
                    acc[r][c] = fmaf(ar[r], br[c], acc[r][c]);
        }
    }

    const int row0 = m0 + ty * 8, col0 = n0 + tx * 8;
    if (flags & F_SHIFT) {
        // rel_shift fold: value computed at (i, jr) belongs at j = jr + i - (qlen-1).
        // Out-of-range j are exactly the causally-masked / never-used slots.
        #pragma unroll
        for (int r = 0; r < 8; ++r) {
            int row = row0 + r;
            if (row >= M) continue;
            #pragma unroll
            for (int c = 0; c < 8; ++c) {
                int jr = col0 + c;
                if (jr >= N) continue;
                int j = jr + row - (M - 1);
                if (j >= 0 && j < N) C[(long)row * ldc + j] += acc[r][c];
            }
        }
    } else {
        #pragma unroll
        for (int r = 0; r < 8; ++r) {
            int row = row0 + r;
            if (row >= M) continue;
            #pragma unroll
            for (int c = 0; c < 8; ++c) {
                int col = col0 + c;
                if (col >= N) continue;
                float v = acc[r][c];
                if (bias) v += bias[col];
                if (flags & F_RELU) v = fmaxf(v, 0.f);
                C[(long)row * ldc + col] = v;
            }
        }
    }
}

// ---------------------------------------------------------------------------

__device__ __forceinline__ float blk_sum(float v, float* sm) {
    #pragma unroll
    for (int m = 32; m; m >>= 1) v += __shfl_xor(v, m, 64);
    int lane = threadIdx.x & 63, w = threadIdx.x >> 6;
    if (lane == 0) sm[w] = v;
    __syncthreads();
    v = sm[0] + sm[1] + sm[2] + sm[3];
    __syncthreads();
    return v;
}

__device__ __forceinline__ float blk_max(float v, float* sm) {
    #pragma unroll
    for (int m = 32; m; m >>= 1) v = fmaxf(v, __shfl_xor(v, m, 64));
    int lane = threadIdx.x & 63, w = threadIdx.x >> 6;
    if (lane == 0) sm[w] = v;
    __syncthreads();
    v = fmaxf(fmaxf(sm[0], sm[1]), fmaxf(sm[2], sm[3]));
    __syncthreads();
    return v;
}

// h[(i*4+b)*1024 + d] = emb[data[i*4+b]*1024 + d] * sqrt(1024)
__global__ __launch_bounds__(256)
void embed_kernel(const int* __restrict__ data, const float* __restrict__ emb,
                  float* __restrict__ h)
{
    long idx = (long)blockIdx.x * 256 + threadIdx.x;   // 2048*1024
    int r = (int)(idx >> 10), d = (int)(idx & 1023);
    h[idx] = emb[(long)data[r] * 1024 + d] * 32.0f;
}

// pos_emb[p][d]: pos = 1023-p; d<512: sin(pos*invf(d)) else cos(pos*invf(d-512))
__global__ __launch_bounds__(256)
void posemb_kernel(float* __restrict__ pe)
{
    int idx = blockIdx.x * 256 + threadIdx.x;          // 1024*1024
    int p = idx >> 10, d = idx & 1023;
    float pos = (float)(1023 - p);
    int j = d & 511;
    float invf = powf(10000.0f, -(float)j * (1.0f / 512.0f));
    float a = pos * invf;
    pe[idx] = (d < 512) ? sinf(a) : cosf(a);
}

// qw/qr[(b*16+n)*512*64 + i*64 + d] = q(heads) + r_w_bias / r_r_bias
__global__ __launch_bounds__(256)
void qwqr_kernel(const float* __restrict__ heads, const float* __restrict__ rwb,
                 const float* __restrict__ rrb, float* __restrict__ qw,
                 float* __restrict__ qr)
{
    int idx = blockIdx.x * 256 + threadIdx.x;          // 4*16*512*64 = 2M
    int d = idx & 63, i = (idx >> 6) & 511, n = (idx >> 15) & 15, b = idx >> 19;
    float v = heads[(long)((512 + i) * 4 + b) * 3072 + n * 64 + d];
    int e = n * 64 + d;
    qw[idx] = v + rwb[e];
    qr[idx] = v + rrb[e];
}

// In-place masked softmax over j (1024) for row (z=b*16+n, i). scale=1/8.
__global__ __launch_bounds__(256)
void softmax_kernel(float* __restrict__ score)
{
    __shared__ float sm[4];
    int i = blockIdx.x, z = blockIdx.y;
    float* row = score + ((long)z * 512 + i) * 1024;
    int t = threadIdx.x;
    int jmax = 512 + i;   // mlen + i; j > jmax is masked
    float v[4];
    #pragma unroll
    for (int u = 0; u < 4; ++u) {
        int j = u * 256 + t;
        float x = row[j] * 0.125f;
        v[u] = (j > jmax) ? -1e30f : x;
    }
    float m = fmaxf(fmaxf(v[0], v[1]), fmaxf(v[2], v[3]));
    m = blk_max(m, sm);
    float e[4];
    float s = 0.f;
    #pragma unroll
    for (int u = 0; u < 4; ++u) { e[u] = expf(v[u] - m); s += e[u]; }
    s = blk_sum(s, sm);
    float inv = 1.0f / s;
    #pragma unroll
    for (int u = 0; u < 4; ++u) row[u * 256 + t] = e[u] * inv;
}

// h[row] = LayerNorm(h[row] + res[row]) * g + b   (in place on h)
__global__ __launch_bounds__(256)
void add_ln_kernel(float* __restrict__ h, const float* __restrict__ res,
                   const float* __restrict__ g, const float* __restrict__ be)
{
    __shared__ float sm[4];
    int row = blockIdx.x, t = threadIdx.x;
    float* hp = h + (long)row * 1024;
    float4 x = *(float4*)(hp + t * 4);
    float4 rv = *(const float4*)(res + (long)row * 1024 + t * 4);
    x.x += rv.x; x.y += rv.y; x.z += rv.z; x.w += rv.w;
    float s = blk_sum(x.x + x.y + x.z + x.w, sm);
    float mu = s * (1.0f / 1024.0f);
    float d0 = x.x - mu, d1 = x.y - mu, d2 = x.z - mu, d3 = x.w - mu;
    float s2 = blk_sum(d0 * d0 + d1 * d1 + d2 * d2 + d3 * d3, sm);
    float inv = rsqrtf(s2 * (1.0f / 1024.0f) + 1e-5f);
    float4 gg = *(const float4*)(g + t * 4);
    float4 bb = *(const float4*)(be + t * 4);
    float4 o;
    o.x = d0 * inv * gg.x + bb.x;
    o.y = d1 * inv * gg.y + bb.y;
    o.z = d2 * inv * gg.z + bb.z;
    o.w = d3 * inv * gg.w + bb.w;
    *(float4*)(hp + t * 4) = o;
}

__global__ void init_ms_kernel(float2* __restrict__ ms)
{
    int i = blockIdx.x * 256 + threadIdx.x;
    if (i < 2048) ms[i] = make_float2(-3e38f, 0.f);
}

// Streaming logsumexp merge over one vocab chunk.
__global__ __launch_bounds__(256)
void merge_kernel(const float* __restrict__ chunk, float2* __restrict__ ms, int CN)
{
    __shared__ float sm[4];
    int row = blockIdx.x, t = threadIdx.x;
    const float* cp = chunk + (long)row * CN;
    float m = -3e38f;
    for (int j = t; j < CN; j += 256) m = fmaxf(m, cp[j]);
    m = blk_max(m, sm);
    float s = 0.f;
    for (int j = t; j < CN; j += 256) s += expf(cp[j] - m);
    s = blk_sum(s, sm);
    if (t == 0) {
        float2 cur = ms[row];
        float nm = fmaxf(cur.x, m);
        ms[row] = make_float2(nm, cur.y * expf(cur.x - nm) + s * expf(m - nm));
    }
}

// loss[row] = logsumexp - (h[row].emb[target] + out_bias[target])
__global__ __launch_bounds__(256)
void final_kernel(const float* __restrict__ h, const float* __restrict__ emb,
                  const float* __restrict__ ob, const int* __restrict__ target,
                  const float2* __restrict__ ms, float* __restrict__ out)
{
    __shared__ float sm[4];
    int row = blockIdx.x, t = threadIdx.x;
    int tok = target[row];
    const float* hp = h + (long)row * 1024;
    const float* ep = emb + (long)tok * 1024;
    float4 a = *(const float4*)(hp + t * 4);
    float4 b = *(const float4*)(ep + t * 4);
    float s = blk_sum(a.x * b.x + a.y * b.y + a.z * b.z + a.w * b.w, sm);
    if (t == 0) {
        float2 v = ms[row];
        out[row] = v.x + logf(v.y) - (s + ob[tok]);
    }
}

// ---------------------------------------------------------------------------

static inline void gemm(hipStream_t st,
    const float* A, int lda, long alo, long ahi, int amod,
    const float* B, int ldb, long blo, long bhi, int bmod,
    float* C, int ldc, long clo, long chi, int cmod,
    const float* bias, int M, int N, int K, int flags, int batch)
{
    dim3 grid((N + 127) / 128, (M + 127) / 128, batch);
    gemm_kernel<<<grid, 256, 0, st>>>(A, lda, alo, ahi, amod,
                                      B, ldb, blo, bhi, bmod,
                                      C, ldc, clo, chi, cmod,
                                      bias, M, N, K, flags);
}

extern "C" void kernel_launch(void* const* d_in, const int* in_sizes, int n_in,
                              void* d_out, int out_size, void* d_ws, size_t ws_size,
                              hipStream_t stream)
{
    const int*   data     = (const int*)d_in[0];
    const int*   target   = (const int*)d_in[1];
    const float* mems     = (const float*)d_in[2];
    const float* emb      = (const float*)d_in[3];
    const float* out_bias = (const float*)d_in[4];
    const float* r_w_bias = (const float*)d_in[5];
    const float* r_r_bias = (const float*)d_in[6];
    const float* qkv_w    = (const float*)d_in[7];
    const float* r_w      = (const float*)d_in[8];
    const float* o_w      = (const float*)d_in[9];
    const float* ln1_g    = (const float*)d_in[10];
    const float* ln1_b    = (const float*)d_in[11];
    const float* ff1_w    = (const float*)d_in[12];
    const float* ff1_b    = (const float*)d_in[13];
    const float* ff2_w    = (const float*)d_in[14];
    const float* ff2_b    = (const float*)d_in[15];
    const float* ln2_g    = (const float*)d_in[16];
    const float* ln2_b    = (const float*)d_in[17];
    float* out = (float*)d_out;
    float* ws  = (float*)d_ws;

    // workspace layout (floats)
    float* h     = ws;                      // 2,097,152   (512*4, 1024)
    float* cat   = h     + 2097152;         // 4,194,304   (1024*4, 1024)
    float* heads = cat   + 4194304;         // 12,582,912  (1024*4, 3072)
    float* pe    = heads + 12582912;        // 1,048,576   (1024, 1024)
    float* rbuf  = pe    + 1048576;         // 1,048,576   (1024, 1024)
    float* qw    = rbuf  + 1048576;         // 2,097,152   (b,n,i,d)
    float* qr    = qw    + 2097152;         // 2,097,152
    float* score = qr    + 2097152;         // 33,554,432  (b,n,512,1024)
    float* attnv = score + 33554432;        // 2,097,152   (i,b,e)
    float* attno = attnv + 2097152;         // 2,097,152
    float* ffo   = attno + 2097152;         // 2,097,152
    float2* ms   = (float2*)(ffo + 2097152);// 2048 float2
    float* ffh   = score;                   // alias: (2048, 4096) fits in score
    float* chunk = score;                   // alias: (2048, 2000) after layers

    embed_kernel<<<8192, 256, 0, stream>>>(data, emb, h);
    posemb_kernel<<<4096, 256, 0, stream>>>(pe);

    for (int l = 0; l < 6; ++l) {
        // cat = [mems[l]; h]
        hipMemcpyAsync(cat, mems + (size_t)l * 2097152, 2097152 * 4,
                       hipMemcpyDeviceToDevice, stream);
        hipMemcpyAsync(cat + 2097152, h, 2097152 * 4,
                       hipMemcpyDeviceToDevice, stream);

        // heads = cat @ qkv_w[l]^T          (4096, 3072)
        gemm(stream, cat, 1024, 0, 0, LINMOD,
             qkv_w + (size_t)l * 3145728, 1024, 0, 0, LINMOD,
             heads, 3072, 0, 0, LINMOD, nullptr, 4096, 3072, 1024, 0, 1);

        // rbuf = pos_emb @ r_w[l]^T         (1024, 1024)
        gemm(stream, pe, 1024, 0, 0, LINMOD,
             r_w + (size_t)l * 1048576, 1024, 0, 0, LINMOD,
             rbuf, 1024, 0, 0, LINMOD, nullptr, 1024, 1024, 1024, 0, 1);

        // qw/qr with biases
        qwqr_kernel<<<8192, 256, 0, stream>>>(heads, r_w_bias, r_r_bias, qw, qr);

        // AC: score[z][i][j] = qw_z . k_z   (batch z=b*16+n; k read from heads)
        gemm(stream, qw, 64, 32768, 0, LINMOD,
             heads + 1024, 12288, 64, 3072, 16,
             score, 1024, 524288, 0, LINMOD, nullptr, 512, 1024, 64, 0, 64);

        // BD with fused rel_shift accumulate (B rows = rbuf[jr], per-n offset)
        gemm(stream, qr, 64, 32768, 0, LINMOD,
             rbuf, 1024, 64, 0, 16,
             score, 1024, 524288, 0, LINMOD, nullptr, 512, 1024, 64, F_SHIFT, 64);

        // masked softmax in place -> prob
        softmax_kernel<<<dim3(512, 64), 256, 0, stream>>>(score);

        // attn_vec[(i*4+b)*1024 + n*64+d] = prob_z @ v_z  (v from heads, B in (K,N))
        gemm(stream, score, 1024, 524288, 0, LINMOD,
             heads + 2048, 12288, 64, 3072, 16,
             attnv, 4096, 64, 1024, 16, nullptr, 512, 64, 1024, F_BNT, 64);

        // attn_out = attn_vec @ o_w[l]^T    (2048, 1024)
        gemm(stream, attnv, 1024, 0, 0, LINMOD,
             o_w + (size_t)l * 1048576, 1024, 0, 0, LINMOD,
             attno, 1024, 0, 0, LINMOD, nullptr, 2048, 1024, 1024, 0, 1);

        // h = LN(h + attn_out)
        add_ln_kernel<<<2048, 256, 0, stream>>>(h, attno, ln1_g + l * 1024, ln1_b + l * 1024);

        // ffh = relu(h @ ff1_w^T + b1)      (2048, 4096)
        gemm(stream, h, 1024, 0, 0, LINMOD,
             ff1_w + (size_t)l * 4194304, 1024, 0, 0, LINMOD,
             ffh, 4096, 0, 0, LINMOD, ff1_b + l * 4096, 2048, 4096, 1024, F_RELU, 1);

        // ffo = ffh @ ff2_w^T + b2          (2048, 1024)
        gemm(stream, ffh, 4096, 0, 0, LINMOD,
             ff2_w + (size_t)l * 4194304, 4096, 0, 0, LINMOD,
             ffo, 1024, 0, 0, LINMOD, ff2_b + l * 1024, 2048, 1024, 4096, 0, 1);

        // h = LN(h + ff)
        add_ln_kernel<<<2048, 256, 0, stream>>>(h, ffo, ln2_g + l * 1024, ln2_b + l * 1024);
    }

    // Streaming logsumexp over vocab in 16 chunks of 2000 (no 262MB logits).
    init_ms_kernel<<<8, 256, 0, stream>>>(ms);
    for (int c = 0; c < 16; ++c) {
        gemm(stream, h, 1024, 0, 0, LINMOD,
             emb + (size_t)c * 2048000, 1024, 0, 0, LINMOD,
             chunk, 2000, 0, 0, LINMOD, out_bias + c * 2000, 2048, 2000, 1024, 0, 1);
        merge_kernel<<<2048, 256, 0, stream>>>(chunk, ms, 2000);
    }
    final_kernel<<<2048, 256, 0, stream>>>(h, emb, out_bias, target, ms, out);
}

// Round 2
// 5785.450 us; speedup vs baseline: 2.7321x; 2.7321x over previous
//
#include <hip/hip_runtime.h>
#include <math.h>

// ---------------------------------------------------------------------------
// TransformerXL forward — bf16 MFMA GEMMs, fp32 residual/LN/softmax-stats.
// QLEN=512 MEM_LEN=512 KLEN=1024 BSZ=4 NH=16 DH=64 DM=1024 DI=4096 V=32000 L=6
// ---------------------------------------------------------------------------

typedef unsigned short u16;
typedef __attribute__((ext_vector_type(8))) short bf16x8;
typedef __attribute__((ext_vector_type(4))) float f32x4;

#define LINMOD (1 << 30)
constexpr int PITCH = 40;   // LDS row pitch in bf16 elems (32 data + 8 pad)

__device__ __forceinline__ u16 f2bf(float f) {
    unsigned u = __float_as_uint(f);
    return (u16)((u + 0x7fffu + ((u >> 16) & 1u)) >> 16);
}
__device__ __forceinline__ float bf2f(u16 b) {
    return __uint_as_float((unsigned)b << 16);
}

// ---------------------------------------------------------------------------
// bf16 MFMA GEMM. C[M,N] = A[M,K] * B^T (B stored [N,K]); KNB=1: B stored
// [K,N] (transposed in LDS). Batched via blockIdx.z: off=(z%mod)*lo+(z/mod)*hi.
// EPI: 0 = fp32 store (+bias,+relu), 1 = bf16 store (+bias,+relu),
//      2 = fp32 rel-shift accumulate (TransformerXL BD term).
// All of M,N,K must be multiples of the tile (they are, by construction).
// ---------------------------------------------------------------------------
template<int BM, int BN, int KNB, int EPI>
__global__ __launch_bounds__(256)
void mgemm(const u16* __restrict__ A, int lda, long alo, long ahi, int amod,
           const u16* __restrict__ B, int ldb, long blo, long bhi, int bmod,
           void* __restrict__ Cv, int ldc, long clo, long chi, int cmod,
           const float* __restrict__ bias, int M, int N, int K, int relu)
{
    constexpr int WM = BM / 2, WN = BN / 2, MT = WM / 16, NT = WN / 16;
    __shared__ u16 As[BM * PITCH];
    __shared__ u16 Bs[BN * PITCH];
    const int z = blockIdx.z;
    A += (long)(z % amod) * alo + (long)(z / amod) * ahi;
    B += (long)(z % bmod) * blo + (long)(z / bmod) * bhi;
    const long coff = (long)(z % cmod) * clo + (long)(z / cmod) * chi;

    const int m0 = blockIdx.y * BM, n0 = blockIdx.x * BN;
    const int t = threadIdx.x;
    const int l = t & 63, w = t >> 6;
    const int wm = w >> 1, wn = w & 1;
    const int fr = l & 15, fq = l >> 4;

    f32x4 acc[MT][NT];
    #pragma unroll
    for (int i = 0; i < MT; ++i)
        #pragma unroll
        for (int j = 0; j < NT; ++j) acc[i][j] = (f32x4){0.f, 0.f, 0.f, 0.f};

    constexpr int AIT = BM * 4 / 256;
    constexpr int BIT = KNB ? (BN / 64) : (BN * 4 / 256);

    const int nk = K / 32;
    for (int kt = 0; kt < nk; ++kt) {
        uint4 av[AIT], bv[BIT];
        #pragma unroll
        for (int i = 0; i < AIT; ++i) {
            int c = t + i * 256, row = c >> 2, q = c & 3;
            av[i] = *(const uint4*)(A + (long)(m0 + row) * lda + kt * 32 + q * 8);
        }
        if constexpr (KNB) {
            #pragma unroll
            for (int i = 0; i < BIT; ++i) {
                int c = t + i * 256, k = c / (BN / 8), n8 = (c % (BN / 8)) * 8;
                bv[i] = *(const uint4*)(B + (long)(kt * 32 + k) * ldb + n0 + n8);
            }
        } else {
            #pragma unroll
            for (int i = 0; i < BIT; ++i) {
                int c = t + i * 256, row = c >> 2, q = c & 3;
                bv[i] = *(const uint4*)(B + (long)(n0 + row) * ldb + kt * 32 + q * 8);
            }
        }
        __syncthreads();
        #pragma unroll
        for (int i = 0; i < AIT; ++i) {
            int c = t + i * 256, row = c >> 2, q = c & 3;
            *(uint4*)&As[row * PITCH + q * 8] = av[i];
        }
        if constexpr (KNB) {
            #pragma unroll
            for (int i = 0; i < BIT; ++i) {
                int c = t + i * 256, k = c / (BN / 8), n8 = (c % (BN / 8)) * 8;
                u16 vals[8];
                *(uint4*)vals = bv[i];
                #pragma unroll
                for (int j = 0; j < 8; ++j) Bs[(n8 + j) * PITCH + k] = vals[j];
            }
        } else {
            #pragma unroll
            for (int i = 0; i < BIT; ++i) {
                int c = t + i * 256, row = c >> 2, q = c & 3;
                *(uint4*)&Bs[row * PITCH + q * 8] = bv[i];
            }
        }
        __syncthreads();
        bf16x8 af[MT], bfr[NT];
        #pragma unroll
        for (int i = 0; i < MT; ++i)
            af[i] = *(const bf16x8*)&As[(wm * WM + i * 16 + fr) * PITCH + fq * 8];
        #pragma unroll
        for (int j = 0; j < NT; ++j)
            bfr[j] = *(const bf16x8*)&Bs[(wn * WN + j * 16 + fr) * PITCH + fq * 8];
        #pragma unroll
        for (int i = 0; i < MT; ++i)
            #pragma unroll
            for (int j = 0; j < NT; ++j)
                acc[i][j] = __builtin_amdgcn_mfma_f32_16x16x32_bf16(
                    af[i], bfr[j], acc[i][j], 0, 0, 0);
    }

    if constexpr (EPI == 2) {
        float* C = (float*)Cv + coff;
        #pragma unroll
        for (int i = 0; i < MT; ++i) {
            int rb = m0 + wm * WM + i * 16 + fq * 4;
            #pragma unroll
            for (int j = 0; j < NT; ++j) {
                int gcol = n0 + wn * WN + j * 16 + fr;
                #pragma unroll
                for (int r = 0; r < 4; ++r) {
                    int row = rb + r;
                    int jj = gcol + row - (M - 1);   // rel-shift fold
                    if (jj >= 0 && jj < N) C[(long)row * ldc + jj] += acc[i][j][r];
                }
            }
        }
    } else if constexpr (EPI == 1) {
        u16* C = (u16*)Cv + coff;
        #pragma unroll
        for (int i = 0; i < MT; ++i) {
            int rb = m0 + wm * WM + i * 16 + fq * 4;
            #pragma unroll
            for (int j = 0; j < NT; ++j) {
                int gcol = n0 + wn * WN + j * 16 + fr;
                float bb = bias ? bias[gcol] : 0.f;
                #pragma unroll
                for (int r = 0; r < 4; ++r) {
                    float v = acc[i][j][r] + bb;
                    if (relu) v = fmaxf(v, 0.f);
                    C[(long)(rb + r) * ldc + gcol] = f2bf(v);
                }
            }
        }
    } else {
        float* C = (float*)Cv + coff;
        #pragma unroll
        for (int i = 0; i < MT; ++i) {
            int rb = m0 + wm * WM + i * 16 + fq * 4;
            #pragma unroll
            for (int j = 0; j < NT; ++j) {
                int gcol = n0 + wn * WN + j * 16 + fr;
                float bb = bias ? bias[gcol] : 0.f;
                #pragma unroll
                for (int r = 0; r < 4; ++r) {
                    float v = acc[i][j][r] + bb;
                    if (relu) v = fmaxf(v, 0.f);
                    C[(long)(rb + r) * ldc + gcol] = v;
                }
            }
        }
    }
}

template<int BM, int BN, int KNB, int EPI>
static inline void mg(hipStream_t st,
    const u16* A, int lda, long alo, long ahi, int amod,
    const u16* B, int ldb, long blo, long bhi, int bmod,
    void* C, int ldc, long clo, long chi, int cmod,
    const float* bias, int M, int N, int K, int relu, int batch)
{
    dim3 grid(N / BN, M / BM, batch);
    mgemm<BM, BN, KNB, EPI><<<grid, 256, 0, st>>>(A, lda, alo, ahi, amod,
        B, ldb, blo, bhi, bmod, C, ldc, clo, chi, cmod, bias, M, N, K, relu);
}

// ---------------------------------------------------------------------------

__device__ __forceinline__ float blk_sum(float v, float* sm) {
    #pragma unroll
    for (int m = 32; m; m >>= 1) v += __shfl_xor(v, m, 64);
    int lane = threadIdx.x & 63, w = threadIdx.x >> 6;
    if (lane == 0) sm[w] = v;
    __syncthreads();
    v = sm[0] + sm[1] + sm[2] + sm[3];
    __syncthreads();
    return v;
}

__device__ __forceinline__ float blk_max(float v, float* sm) {
    #pragma unroll
    for (int m = 32; m; m >>= 1) v = fmaxf(v, __shfl_xor(v, m, 64));
    int lane = threadIdx.x & 63, w = threadIdx.x >> 6;
    if (lane == 0) sm[w] = v;
    __syncthreads();
    v = fmaxf(fmaxf(sm[0], sm[1]), fmaxf(sm[2], sm[3]));
    __syncthreads();
    return v;
}

// fp32 -> bf16 elementwise (n4 = n/4 float4 groups)
__global__ __launch_bounds__(256)
void f2b_kernel(const float* __restrict__ in, u16* __restrict__ out, int n4)
{
    int i = blockIdx.x * 256 + threadIdx.x;
    if (i >= n4) return;
    float4 v = ((const float4*)in)[i];
    uint2 o;
    o.x = (unsigned)f2bf(v.x) | ((unsigned)f2bf(v.y) << 16);
    o.y = (unsigned)f2bf(v.z) | ((unsigned)f2bf(v.w) << 16);
    ((uint2*)out)[i] = o;
}

// cat = bf16([mems[l]; h]) : 4096x1024
__global__ __launch_bounds__(256)
void cat_kernel(const float* __restrict__ memsl, const float* __restrict__ h,
                u16* __restrict__ cat)
{
    int i = blockIdx.x * 256 + threadIdx.x;       // 1,048,576 float4 groups
    float4 v = (i < 524288) ? ((const float4*)memsl)[i]
                            : ((const float4*)h)[i - 524288];
    uint2 o;
    o.x = (unsigned)f2bf(v.x) | ((unsigned)f2bf(v.y) << 16);
    o.y = (unsigned)f2bf(v.z) | ((unsigned)f2bf(v.w) << 16);
    ((uint2*)cat)[i] = o;
}

// h[(i*4+b)*1024+d] = emb[data]*32  (fp32 master)
__global__ __launch_bounds__(256)
void embed_kernel(const int* __restrict__ data, const float* __restrict__ emb,
                  float* __restrict__ h)
{
    long idx = (long)blockIdx.x * 256 + threadIdx.x;   // 2048*1024
    int r = (int)(idx >> 10), d = (int)(idx & 1023);
    h[idx] = emb[(long)data[r] * 1024 + d] * 32.0f;
}

// sinusoidal pos emb, descending positions, written as bf16
__global__ __launch_bounds__(256)
void posemb_kernel(u16* __restrict__ pe)
{
    int idx = blockIdx.x * 256 + threadIdx.x;          // 1024*1024
    int p = idx >> 10, d = idx & 1023;
    float pos = (float)(1023 - p);
    int j = d & 511;
    float invf = powf(10000.0f, -(float)j * (1.0f / 512.0f));
    float a = pos * invf;
    pe[idx] = f2bf((d < 512) ? sinf(a) : cosf(a));
}

// qw/qr[(b*16+n)*512*64 + i*64 + d] = q + r_w_bias / r_r_bias   (bf16)
__global__ __launch_bounds__(256)
void qwqr_kernel(const u16* __restrict__ heads, const float* __restrict__ rwb,
                 const float* __restrict__ rrb, u16* __restrict__ qw,
                 u16* __restrict__ qr)
{
    int idx = blockIdx.x * 256 + threadIdx.x;          // 2M
    int d = idx & 63, i = (idx >> 6) & 511, n = (idx >> 15) & 15, b = idx >> 19;
    float v = bf2f(heads[(long)((512 + i) * 4 + b) * 3072 + n * 64 + d]);
    int e = n * 64 + d;
    qw[idx] = f2bf(v + rwb[e]);
    qr[idx] = f2bf(v + rrb[e]);
}

// masked softmax over j; reads fp32 row, writes bf16 probs in-place (row slot)
__global__ __launch_bounds__(256)
void softmax_kernel(float* __restrict__ score)
{
    __shared__ float sm[4];
    int i = blockIdx.x, z = blockIdx.y;
    float* row = score + ((long)z * 512 + i) * 1024;
    int t = threadIdx.x;
    int jmax = 512 + i;
    float v[4];
    #pragma unroll
    for (int u = 0; u < 4; ++u) {
        int j = u * 256 + t;
        float x = row[j] * 0.125f;
        v[u] = (j > jmax) ? -1e30f : x;
    }
    float m = fmaxf(fmaxf(v[0], v[1]), fmaxf(v[2], v[3]));
    m = blk_max(m, sm);
    float e[4];
    float s = 0.f;
    #pragma unroll
    for (int u = 0; u < 4; ++u) { e[u] = expf(v[u] - m); s += e[u]; }
    s = blk_sum(s, sm);
    float inv = 1.0f / s;
    u16* op = (u16*)row;   // bf16 probs, row pitch 2048 elems (same 4KB slot)
    #pragma unroll
    for (int u = 0; u < 4; ++u) op[u * 256 + t] = f2bf(e[u] * inv);
}

// h = LN(h + res) * g + b   (fp32, in place)
__global__ __launch_bounds__(256)
void add_ln_kernel(float* __restrict__ h, const float* __restrict__ res,
                   const float* __restrict__ g, const float* __restrict__ be)
{
    __shared__ float sm[4];
    int row = blockIdx.x, t = threadIdx.x;
    float* hp = h + (long)row * 1024;
    float4 x = *(float4*)(hp + t * 4);
    float4 rv = *(const float4*)(res + (long)row * 1024 + t * 4);
    x.x += rv.x; x.y += rv.y; x.z += rv.z; x.w += rv.w;
    float s = blk_sum(x.x + x.y + x.z + x.w, sm);
    float mu = s * (1.0f / 1024.0f);
    float d0 = x.x - mu, d1 = x.y - mu, d2 = x.z - mu, d3 = x.w - mu;
    float s2 = blk_sum(d0 * d0 + d1 * d1 + d2 * d2 + d3 * d3, sm);
    float inv = rsqrtf(s2 * (1.0f / 1024.0f) + 1e-5f);
    float4 gg = *(const float4*)(g + t * 4);
    float4 bb = *(const float4*)(be + t * 4);
    float4 o;
    o.x = d0 * inv * gg.x + bb.x;
    o.y = d1 * inv * gg.y + bb.y;
    o.z = d2 * inv * gg.z + bb.z;
    o.w = d3 * inv * gg.w + bb.w;
    *(float4*)(hp + t * 4) = o;
}

__global__ void init_ms_kernel(float2* __restrict__ ms)
{
    int i = blockIdx.x * 256 + threadIdx.x;
    if (i < 2048) ms[i] = make_float2(-3e38f, 0.f);
}

__global__ __launch_bounds__(256)
void merge_kernel(const float* __restrict__ chunk, float2* __restrict__ ms, int CN)
{
    __shared__ float sm[4];
    int row = blockIdx.x, t = threadIdx.x;
    const float* cp = chunk + (long)row * CN;
    float m = -3e38f;
    for (int j = t; j < CN; j += 256) m = fmaxf(m, cp[j]);
    m = blk_max(m, sm);
    float s = 0.f;
    for (int j = t; j < CN; j += 256) s += expf(cp[j] - m);
    s = blk_sum(s, sm);
    if (t == 0) {
        float2 cur = ms[row];
        float nm = fmaxf(cur.x, m);
        ms[row] = make_float2(nm, cur.y * expf(cur.x - nm) + s * expf(m - nm));
    }
}

__global__ __launch_bounds__(256)
void final_kernel(const float* __restrict__ h, const float* __restrict__ emb,
                  const float* __restrict__ ob, const int* __restrict__ target,
                  const float2* __restrict__ ms, float* __restrict__ out)
{
    __shared__ float sm[4];
    int row = blockIdx.x, t = threadIdx.x;
    int tok = target[row];
    const float* hp = h + (long)row * 1024;
    const float* ep = emb + (long)tok * 1024;
    float4 a = *(const float4*)(hp + t * 4);
    float4 b = *(const float4*)(ep + t * 4);
    float s = blk_sum(a.x * b.x + a.y * b.y + a.z * b.z + a.w * b.w, sm);
    if (t == 0) {
        float2 v = ms[row];
        out[row] = v.x + logf(v.y) - (s + ob[tok]);
    }
}

// ---------------------------------------------------------------------------

extern "C" void kernel_launch(void* const* d_in, const int* in_sizes, int n_in,
                              void* d_out, int out_size, void* d_ws, size_t ws_size,
                              hipStream_t stream)
{
    const int*   data     = (const int*)d_in[0];
    const int*   target   = (const int*)d_in[1];
    const float* mems     = (const float*)d_in[2];
    const float* emb      = (const float*)d_in[3];
    const float* out_bias = (const float*)d_in[4];
    const float* r_w_bias = (const float*)d_in[5];
    const float* r_r_bias = (const float*)d_in[6];
    const float* qkv_w    = (const float*)d_in[7];
    const float* r_w      = (const float*)d_in[8];
    const float* o_w      = (const float*)d_in[9];
    const float* ln1_g    = (const float*)d_in[10];
    const float* ln1_b    = (const float*)d_in[11];
    const float* ff1_w    = (const float*)d_in[12];
    const float* ff1_b    = (const float*)d_in[13];
    const float* ff2_w    = (const float*)d_in[14];
    const float* ff2_b    = (const float*)d_in[15];
    const float* ln2_g    = (const float*)d_in[16];
    const float* ln2_b    = (const float*)d_in[17];
    float* out = (float*)d_out;
    float* ws  = (float*)d_ws;

    // workspace layout (float offsets); total ~233 MB
    float* h       = ws;                            // 2,097,152 f
    float* tmp     = ws + 2097152;                  // 2,097,152 f (attno/ffo)
    u16*  pe_bf    = (u16*)(ws + 4194304);          // 1M bf16
    u16*  rbuf_bf  = (u16*)(ws + 4718592);          // 1M bf16
    u16*  cat_bf   = (u16*)(ws + 5242880);          // 4M bf16
    u16*  heads_bf = (u16*)(ws + 7340032);          // 12.58M bf16
    u16*  qw_bf    = (u16*)(ws + 13631488);         // 2M bf16
    u16*  qr_bf    = (u16*)(ws + 14680064);         // 2M bf16
    u16*  attnv_bf = (u16*)(ws + 15728640);         // 2M bf16
    u16*  h_bf     = (u16*)(ws + 16777216);         // 1M bf16
    u16*  wqkv     = (u16*)(ws + 17825792);         // 3.15M bf16
    u16*  wr       = wqkv + 3145728;                // 1M
    u16*  wo       = wr + 1048576;                  // 1M
    u16*  wf1      = wo + 1048576;                  // 4.19M
    u16*  wf2      = wf1 + 4194304;                 // 4.19M  (ends 24641536 f)
    float* score   = ws + 24641536;                 // 33,554,432 f
    float2* ms     = (float2*)(ws + 58195968);      // 2048 float2
    u16*  prob     = (u16*)score;                   // bf16 in-slot, pitch 2048
    u16*  ffh_bf   = (u16*)score;                   // 2048x4096 bf16 (aliased)
    float* chunk   = score;                         // 2048x8192 f (aliased)
    u16*  embc_bf  = (u16*)(score + 16777216);      // 8192x1024 bf16 (aliased)

    embed_kernel<<<8192, 256, 0, stream>>>(data, emb, h);
    posemb_kernel<<<4096, 256, 0, stream>>>(pe_bf);

    for (int l = 0; l < 6; ++l) {
        f2b_kernel<<<3072, 256, 0, stream>>>(qkv_w + (size_t)l * 3145728, wqkv, 786432);
        f2b_kernel<<<1024, 256, 0, stream>>>(r_w + (size_t)l * 1048576, wr, 262144);
        f2b_kernel<<<1024, 256, 0, stream>>>(o_w + (size_t)l * 1048576, wo, 262144);
        f2b_kernel<<<4096, 256, 0, stream>>>(ff1_w + (size_t)l * 4194304, wf1, 1048576);
        f2b_kernel<<<4096, 256, 0, stream>>>(ff2_w + (size_t)l * 4194304, wf2, 1048576);
        cat_kernel<<<4096, 256, 0, stream>>>(mems + (size_t)l * 2097152, h, cat_bf);

        // heads(bf16) = cat @ qkv^T        (4096,3072,1024)
        mg<128,128,0,1>(stream, cat_bf, 1024, 0, 0, LINMOD, wqkv, 1024, 0, 0, LINMOD,
                        heads_bf, 3072, 0, 0, LINMOD, nullptr, 4096, 3072, 1024, 0, 1);
        // rbuf(bf16) = pos_emb @ r_w^T     (1024,1024,1024)
        mg<128,128,0,1>(stream, pe_bf, 1024, 0, 0, LINMOD, wr, 1024, 0, 0, LINMOD,
                        rbuf_bf, 1024, 0, 0, LINMOD, nullptr, 1024, 1024, 1024, 0, 1);

        qwqr_kernel<<<8192, 256, 0, stream>>>(heads_bf, r_w_bias, r_r_bias, qw_bf, qr_bf);

        // AC: score(f32) = qw . k          batch z=b*16+n, (512,1024,64)
        mg<128,128,0,0>(stream, qw_bf, 64, 32768, 0, LINMOD,
                        heads_bf + 1024, 12288, 64, 3072, 16,
                        score, 1024, 524288, 0, LINMOD, nullptr, 512, 1024, 64, 0, 64);
        // BD: score += rel_shift(qr . r)
        mg<128,128,0,2>(stream, qr_bf, 64, 32768, 0, LINMOD,
                        rbuf_bf, 1024, 64, 0, 16,
                        score, 1024, 524288, 0, LINMOD, nullptr, 512, 1024, 64, 0, 64);

        softmax_kernel<<<dim3(512, 64), 256, 0, stream>>>(score);

        // attn_vec(bf16,(i,b,e)) = prob @ v   (512,64,1024), B in (K,N)
        mg<128,64,1,1>(stream, prob, 2048, 1048576, 0, LINMOD,
                       heads_bf + 2048, 12288, 64, 3072, 16,
                       attnv_bf, 4096, 64, 1024, 16, nullptr, 512, 64, 1024, 0, 64);
        // attn_out(f32) = attn_vec @ o_w^T  (2048,1024,1024)
        mg<128,128,0,0>(stream, attnv_bf, 1024, 0, 0, LINMOD, wo, 1024, 0, 0, LINMOD,
                        tmp, 1024, 0, 0, LINMOD, nullptr, 2048, 1024, 1024, 0, 1);

        add_ln_kernel<<<2048, 256, 0, stream>>>(h, tmp, ln1_g + l * 1024, ln1_b + l * 1024);
        f2b_kernel<<<2048, 256, 0, stream>>>(h, h_bf, 524288);

        // ffh(bf16) = relu(h @ ff1^T + b1)  (2048,4096,1024)
        mg<128,128,0,1>(stream, h_bf, 1024, 0, 0, LINMOD, wf1, 1024, 0, 0, LINMOD,
                        ffh_bf, 4096, 0, 0, LINMOD, ff1_b + l * 4096, 2048, 4096, 1024, 1, 1);
        // ffo(f32) = ffh @ ff2^T + b2       (2048,1024,4096)
        mg<128,128,0,0>(stream, ffh_bf, 4096, 0, 0, LINMOD, wf2, 4096, 0, 0, LINMOD,
                        tmp, 1024, 0, 0, LINMOD, ff2_b + l * 1024, 2048, 1024, 4096, 0, 1);

        add_ln_kernel<<<2048, 256, 0, stream>>>(h, tmp, ln2_g + l * 1024, ln2_b + l * 1024);
    }

    f2b_kernel<<<2048, 256, 0, stream>>>(h, h_bf, 524288);
    init_ms_kernel<<<8, 256, 0, stream>>>(ms);

    // logits in 4 bf16 chunks (8192,8192,8192,7424 = 32000), streaming LSE
    const int chunkN[4] = {8192, 8192, 8192, 7424};
    long off = 0;
    for (int c = 0; c < 4; ++c) {
        int CN = chunkN[c];
        int n4 = CN * 1024 / 4;
        f2b_kernel<<<(n4 + 255) / 256, 256, 0, stream>>>(emb + off * 1024, embc_bf, n4);
        mg<128,128,0,0>(stream, h_bf, 1024, 0, 0, LINMOD, embc_bf, 1024, 0, 0, LINMOD,
                        chunk, CN, 0, 0, LINMOD, out_bias + off, 2048, CN, 1024, 0, 1);
        merge_kernel<<<2048, 256, 0, stream>>>(chunk, ms, CN);
        off += CN;
    }
    final_kernel<<<2048, 256, 0, stream>>>(h, emb, out_bias, target, ms, out);
}

// Round 3
// 3487.909 us; speedup vs baseline: 4.5317x; 1.6587x over previous
//
#include <hip/hip_runtime.h>
#include <math.h>

// ---------------------------------------------------------------------------
// TransformerXL forward — bf16 MFMA GEMMs + fused flash-style rel-attention.
// QLEN=512 MEM_LEN=512 KLEN=1024 BSZ=4 NH=16 DH=64 DM=1024 DI=4096 V=32000 L=6
// ---------------------------------------------------------------------------

typedef unsigned short u16;
typedef __attribute__((ext_vector_type(8))) short bf16x8;
typedef __attribute__((ext_vector_type(4))) float f32x4;

#define LINMOD (1 << 30)
constexpr int PITCH = 40;   // mgemm LDS row pitch (32 data + 8 pad)

__device__ __forceinline__ u16 f2bf(float f) {
    unsigned u = __float_as_uint(f);
    return (u16)((u + 0x7fffu + ((u >> 16) & 1u)) >> 16);
}
__device__ __forceinline__ float bf2f(u16 b) {
    return __uint_as_float((unsigned)b << 16);
}

// ---------------------------------------------------------------------------
// bf16 MFMA GEMM (tiles BM x BN, K multiple of 32). C = A[M,K] * B[N,K]^T.
// EPI: 0 = fp32 store (+bias,+relu), 1 = bf16 store (+bias,+relu).
// Batched via blockIdx.z: off = (z%mod)*lo + (z/mod)*hi.
// ---------------------------------------------------------------------------
template<int BM, int BN, int EPI>
__global__ __launch_bounds__(256)
void mgemm(const u16* __restrict__ A, int lda, long alo, long ahi, int amod,
           const u16* __restrict__ B, int ldb, long blo, long bhi, int bmod,
           void* __restrict__ Cv, int ldc, long clo, long chi, int cmod,
           const float* __restrict__ bias, int M, int N, int K, int relu)
{
    constexpr int WM = BM / 2, WN = BN / 2, MT = WM / 16, NT = WN / 16;
    __shared__ u16 As[BM * PITCH];
    __shared__ u16 Bs[BN * PITCH];
    const int z = blockIdx.z;
    A += (long)(z % amod) * alo + (long)(z / amod) * ahi;
    B += (long)(z % bmod) * blo + (long)(z / bmod) * bhi;
    const long coff = (long)(z % cmod) * clo + (long)(z / cmod) * chi;

    const int m0 = blockIdx.y * BM, n0 = blockIdx.x * BN;
    const int t = threadIdx.x;
    const int l = t & 63, w = t >> 6;
    const int wm = w >> 1, wn = w & 1;
    const int fr = l & 15, fq = l >> 4;

    f32x4 acc[MT][NT];
    #pragma unroll
    for (int i = 0; i < MT; ++i)
        #pragma unroll
        for (int j = 0; j < NT; ++j) acc[i][j] = (f32x4){0.f, 0.f, 0.f, 0.f};

    constexpr int AIT = BM * 4 / 256;
    constexpr int BIT = BN * 4 / 256;

    const int nk = K / 32;
    for (int kt = 0; kt < nk; ++kt) {
        uint4 av[AIT], bv[BIT];
        #pragma unroll
        for (int i = 0; i < AIT; ++i) {
            int c = t + i * 256, row = c >> 2, q = c & 3;
            av[i] = *(const uint4*)(A + (long)(m0 + row) * lda + kt * 32 + q * 8);
        }
        #pragma unroll
        for (int i = 0; i < BIT; ++i) {
            int c = t + i * 256, row = c >> 2, q = c & 3;
            bv[i] = *(const uint4*)(B + (long)(n0 + row) * ldb + kt * 32 + q * 8);
        }
        __syncthreads();
        #pragma unroll
        for (int i = 0; i < AIT; ++i) {
            int c = t + i * 256, row = c >> 2, q = c & 3;
            *(uint4*)&As[row * PITCH + q * 8] = av[i];
        }
        #pragma unroll
        for (int i = 0; i < BIT; ++i) {
            int c = t + i * 256, row = c >> 2, q = c & 3;
            *(uint4*)&Bs[row * PITCH + q * 8] = bv[i];
        }
        __syncthreads();
        bf16x8 af[MT], bfr[NT];
        #pragma unroll
        for (int i = 0; i < MT; ++i)
            af[i] = *(const bf16x8*)&As[(wm * WM + i * 16 + fr) * PITCH + fq * 8];
        #pragma unroll
        for (int j = 0; j < NT; ++j)
            bfr[j] = *(const bf16x8*)&Bs[(wn * WN + j * 16 + fr) * PITCH + fq * 8];
        #pragma unroll
        for (int i = 0; i < MT; ++i)
            #pragma unroll
            for (int j = 0; j < NT; ++j)
                acc[i][j] = __builtin_amdgcn_mfma_f32_16x16x32_bf16(
                    af[i], bfr[j], acc[i][j], 0, 0, 0);
    }

    if constexpr (EPI == 1) {
        u16* C = (u16*)Cv + coff;
        #pragma unroll
        for (int i = 0; i < MT; ++i) {
            int rb = m0 + wm * WM + i * 16 + fq * 4;
            #pragma unroll
            for (int j = 0; j < NT; ++j) {
                int gcol = n0 + wn * WN + j * 16 + fr;
                float bb = bias ? bias[gcol] : 0.f;
                #pragma unroll
                for (int r = 0; r < 4; ++r) {
                    float v = acc[i][j][r] + bb;
                    if (relu) v = fmaxf(v, 0.f);
                    C[(long)(rb + r) * ldc + gcol] = f2bf(v);
                }
            }
        }
    } else {
        float* C = (float*)Cv + coff;
        #pragma unroll
        for (int i = 0; i < MT; ++i) {
            int rb = m0 + wm * WM + i * 16 + fq * 4;
            #pragma unroll
            for (int j = 0; j < NT; ++j) {
                int gcol = n0 + wn * WN + j * 16 + fr;
                float bb = bias ? bias[gcol] : 0.f;
                #pragma unroll
                for (int r = 0; r < 4; ++r) {
                    float v = acc[i][j][r] + bb;
                    if (relu) v = fmaxf(v, 0.f);
                    C[(long)(rb + r) * ldc + gcol] = v;
                }
            }
        }
    }
}

template<int BM, int BN, int EPI>
static inline void mg(hipStream_t st,
    const u16* A, int lda, long alo, long ahi, int amod,
    const u16* B, int ldb, long blo, long bhi, int bmod,
    void* C, int ldc, long clo, long chi, int cmod,
    const float* bias, int M, int N, int K, int relu, int batch)
{
    dim3 grid(N / BN, M / BM, batch);
    mgemm<BM, BN, EPI><<<grid, 256, 0, st>>>(A, lda, alo, ahi, amod,
        B, ldb, blo, bhi, bmod, C, ldc, clo, chi, cmod, bias, M, N, K, relu);
}

// ---------------------------------------------------------------------------
// Fused rel-attention: per block (z = b*16+n, i-tile of 128 rows).
// AC = (q+rwb)K^T via MFMA; BD = (q+rrb)R^T computed per 128-wide jr-tile
// (rolling 2-slot LDS rotation, slot also reused for P); rel-shift applied
// when assembling the score; online softmax; PV accumulated in registers.
// ---------------------------------------------------------------------------
__global__ __launch_bounds__(256)
void attn_kernel(const u16* __restrict__ qw, const u16* __restrict__ qr,
                 const u16* __restrict__ heads, const u16* __restrict__ rbuf,
                 u16* __restrict__ attnv)
{
    __shared__ u16 sm[80384];
    __shared__ float pmax[2][128];
    __shared__ float psum[2][128];
    u16* qw_s = sm;             // 128x72
    u16* qr_s = sm + 9216;      // 128x72
    u16* k_s  = sm + 18432;     // 128x72
    u16* r_s  = sm + 27648;     // 128x72
    u16* vT_s = sm + 36864;     // 64x136 (V transposed)
    u16* bd0  = sm + 45568;     // 128x136 (BD/P rotating slots)
    u16* bd1  = sm + 62976;     // 128x136

    const int zz = blockIdx.x, b = zz >> 4, n = zz & 15;
    const int i0 = blockIdx.y * 128;
    const int t = threadIdx.x, l = t & 63, w = t >> 6;
    const int fr = l & 15, fq = l >> 4, wm = w >> 1, wn = w & 1;

    // ---- stage q tiles (persistent) + first r tile (jr0 = 384 - i0) ----
    const u16* qwg = qw + (long)zz * 32768 + (long)i0 * 64;
    const u16* qrg = qr + (long)zz * 32768 + (long)i0 * 64;
    {
        int jr0 = 384 - i0;
        #pragma unroll
        for (int it = 0; it < 4; ++it) {
            int idx = t + it * 256, row = idx >> 3, q8 = idx & 7;
            *(uint4*)&qw_s[row * 72 + q8 * 8] = *(const uint4*)&qwg[row * 64 + q8 * 8];
            *(uint4*)&qr_s[row * 72 + q8 * 8] = *(const uint4*)&qrg[row * 64 + q8 * 8];
            *(uint4*)&r_s[row * 72 + q8 * 8] =
                *(const uint4*)&rbuf[(long)(jr0 + row) * 1024 + n * 64 + q8 * 8];
        }
    }
    __syncthreads();

    // BD tile compute: (qr_s x r_s^T) -> bf16 LDS slot
    auto computeBD = [&](u16* out) {
        f32x4 bacc[4][4];
        #pragma unroll
        for (int i = 0; i < 4; ++i)
            #pragma unroll
            for (int j = 0; j < 4; ++j) bacc[i][j] = (f32x4){0.f, 0.f, 0.f, 0.f};
        #pragma unroll
        for (int ks = 0; ks < 2; ++ks) {
            bf16x8 af[4], bfr[4];
            #pragma unroll
            for (int i = 0; i < 4; ++i)
                af[i] = *(const bf16x8*)&qr_s[(wm * 64 + i * 16 + fr) * 72 + ks * 32 + fq * 8];
            #pragma unroll
            for (int j = 0; j < 4; ++j)
                bfr[j] = *(const bf16x8*)&r_s[(wn * 64 + j * 16 + fr) * 72 + ks * 32 + fq * 8];
            #pragma unroll
            for (int i = 0; i < 4; ++i)
                #pragma unroll
                for (int j = 0; j < 4; ++j)
                    bacc[i][j] = __builtin_amdgcn_mfma_f32_16x16x32_bf16(
                        af[i], bfr[j], bacc[i][j], 0, 0, 0);
        }
        #pragma unroll
        for (int i = 0; i < 4; ++i)
            #pragma unroll
            for (int j = 0; j < 4; ++j)
                #pragma unroll
                for (int r = 0; r < 4; ++r)
                    out[(wm * 64 + i * 16 + fq * 4 + r) * 136 + wn * 64 + j * 16 + fr] =
                        f2bf(bacc[i][j][r]);
    };
    computeBD(bd0);

    float m_st[4][4], l_st[4][4];
    #pragma unroll
    for (int i = 0; i < 4; ++i)
        #pragma unroll
        for (int r = 0; r < 4; ++r) { m_st[i][r] = -3e38f; l_st[i][r] = 0.f; }
    f32x4 Oa[4][2];
    #pragma unroll
    for (int i = 0; i < 4; ++i)
        #pragma unroll
        for (int j = 0; j < 2; ++j) Oa[i][j] = (f32x4){0.f, 0.f, 0.f, 0.f};

    const int ntiles = (640 + i0) >> 7;
    for (int tt = 0; tt < ntiles; ++tt) {
        const int j0 = tt << 7;
        const int jr0b = j0 - i0 + 512;
        u16* bda = (tt & 1) ? bd1 : bd0;
        u16* bdb = (tt & 1) ? bd0 : bd1;

        __syncthreads();   // protect k/r/vT/P from previous iteration's readers

        // ---- stage k, vT (transposed), next r ----
        #pragma unroll
        for (int it = 0; it < 4; ++it) {
            int idx = t + it * 256, row = idx >> 3, q8 = idx & 7;
            long hb = ((long)(j0 + row) * 4 + b) * 3072 + n * 64 + q8 * 8;
            *(uint4*)&k_s[row * 72 + q8 * 8] = *(const uint4*)&heads[hb + 1024];
            uint4 vv = *(const uint4*)&heads[hb + 2048];
            u16 vt[8]; *(uint4*)vt = vv;
            #pragma unroll
            for (int d = 0; d < 8; ++d) vT_s[(q8 * 8 + d) * 136 + row] = vt[d];
            if (jr0b < 1024)
                *(uint4*)&r_s[row * 72 + q8 * 8] =
                    *(const uint4*)&rbuf[(long)(jr0b + row) * 1024 + n * 64 + q8 * 8];
        }
        __syncthreads();

        // ---- BD for next jr tile ----
        if (jr0b < 1024) computeBD(bdb);

        // ---- AC MFMA ----
        f32x4 acc[4][4];
        #pragma unroll
        for (int i = 0; i < 4; ++i)
            #pragma unroll
            for (int j = 0; j < 4; ++j) acc[i][j] = (f32x4){0.f, 0.f, 0.f, 0.f};
        #pragma unroll
        for (int ks = 0; ks < 2; ++ks) {
            bf16x8 af[4], bfr[4];
            #pragma unroll
            for (int i = 0; i < 4; ++i)
                af[i] = *(const bf16x8*)&qw_s[(wm * 64 + i * 16 + fr) * 72 + ks * 32 + fq * 8];
            #pragma unroll
            for (int j = 0; j < 4; ++j)
                bfr[j] = *(const bf16x8*)&k_s[(wn * 64 + j * 16 + fr) * 72 + ks * 32 + fq * 8];
            #pragma unroll
            for (int i = 0; i < 4; ++i)
                #pragma unroll
                for (int j = 0; j < 4; ++j)
                    acc[i][j] = __builtin_amdgcn_mfma_f32_16x16x32_bf16(
                        af[i], bfr[j], acc[i][j], 0, 0, 0);
        }
        __syncthreads();   // BD tile visible

        // ---- score assembly (+BD shift, mask, scale) and row max ----
        const int Dl = j0 - i0;
        float rm[4][4];
        #pragma unroll
        for (int i = 0; i < 4; ++i)
            #pragma unroll
            for (int r = 0; r < 4; ++r) rm[i][r] = -3e38f;
        #pragma unroll
        for (int i = 0; i < 4; ++i) {
            #pragma unroll
            for (int r = 0; r < 4; ++r) {
                int ii = wm * 64 + i * 16 + fq * 4 + r;
                #pragma unroll
                for (int j = 0; j < 4; ++j) {
                    int jj = wn * 64 + j * 16 + fr;
                    int d = jj - ii;
                    int idx = 127 + d;
                    u16 bv = (idx < 128) ? bda[ii * 136 + idx] : bdb[ii * 136 + idx - 128];
                    float sv = (acc[i][j][r] + bf2f(bv)) * 0.125f;
                    sv = (Dl + d > 512) ? -1e30f : sv;
                    acc[i][j][r] = sv;
                    rm[i][r] = fmaxf(rm[i][r], sv);
                }
            }
        }
        #pragma unroll
        for (int i = 0; i < 4; ++i)
            #pragma unroll
            for (int r = 0; r < 4; ++r) {
                float v = rm[i][r];
                v = fmaxf(v, __shfl_xor(v, 1, 64));
                v = fmaxf(v, __shfl_xor(v, 2, 64));
                v = fmaxf(v, __shfl_xor(v, 4, 64));
                v = fmaxf(v, __shfl_xor(v, 8, 64));
                rm[i][r] = v;
            }
        if (fr == 0) {
            #pragma unroll
            for (int i = 0; i < 4; ++i)
                #pragma unroll
                for (int r = 0; r < 4; ++r)
                    pmax[wn][wm * 64 + i * 16 + fq * 4 + r] = rm[i][r];
        }
        __syncthreads();

        // ---- online softmax: m/alpha, P -> LDS, partial sums, O rescale ----
        float alpha[4][4];
        #pragma unroll
        for (int i = 0; i < 4; ++i)
            #pragma unroll
            for (int r = 0; r < 4; ++r) {
                int row = wm * 64 + i * 16 + fq * 4 + r;
                float tm = fmaxf(pmax[0][row], pmax[1][row]);
                float mn = fmaxf(m_st[i][r], tm);
                alpha[i][r] = __expf(m_st[i][r] - mn);
                m_st[i][r] = mn;
            }
        u16* Pp = bda;   // BDa slot is dead now; becomes P
        float rs[4][4];
        #pragma unroll
        for (int i = 0; i < 4; ++i)
            #pragma unroll
            for (int r = 0; r < 4; ++r) rs[i][r] = 0.f;
        #pragma unroll
        for (int i = 0; i < 4; ++i) {
            #pragma unroll
            for (int r = 0; r < 4; ++r) {
                int row = wm * 64 + i * 16 + fq * 4 + r;
                #pragma unroll
                for (int j = 0; j < 4; ++j) {
                    float p = __expf(acc[i][j][r] - m_st[i][r]);
                    rs[i][r] += p;
                    Pp[row * 136 + wn * 64 + j * 16 + fr] = f2bf(p);
                }
            }
        }
        #pragma unroll
        for (int i = 0; i < 4; ++i)
            #pragma unroll
            for (int r = 0; r < 4; ++r) {
                float v = rs[i][r];
                v += __shfl_xor(v, 1, 64);
                v += __shfl_xor(v, 2, 64);
                v += __shfl_xor(v, 4, 64);
                v += __shfl_xor(v, 8, 64);
                rs[i][r] = v;
            }
        if (fr == 0) {
            #pragma unroll
            for (int i = 0; i < 4; ++i)
                #pragma unroll
                for (int r = 0; r < 4; ++r)
                    psum[wn][wm * 64 + i * 16 + fq * 4 + r] = rs[i][r];
        }
        #pragma unroll
        for (int i = 0; i < 4; ++i)
            #pragma unroll
            for (int j = 0; j < 2; ++j)
                #pragma unroll
                for (int r = 0; r < 4; ++r) Oa[i][j][r] *= alpha[i][r];
        __syncthreads();

        // ---- l update + PV MFMA ----
        #pragma unroll
        for (int i = 0; i < 4; ++i)
            #pragma unroll
            for (int r = 0; r < 4; ++r) {
                int row = wm * 64 + i * 16 + fq * 4 + r;
                l_st[i][r] = alpha[i][r] * l_st[i][r] + psum[0][row] + psum[1][row];
            }
        #pragma unroll
        for (int ks = 0; ks < 4; ++ks) {
            bf16x8 pa[4], vb[2];
            #pragma unroll
            for (int i = 0; i < 4; ++i)
                pa[i] = *(const bf16x8*)&Pp[(wm * 64 + i * 16 + fr) * 136 + ks * 32 + fq * 8];
            #pragma unroll
            for (int j = 0; j < 2; ++j)
                vb[j] = *(const bf16x8*)&vT_s[(wn * 32 + j * 16 + fr) * 136 + ks * 32 + fq * 8];
            #pragma unroll
            for (int i = 0; i < 4; ++i)
                #pragma unroll
                for (int j = 0; j < 2; ++j)
                    Oa[i][j] = __builtin_amdgcn_mfma_f32_16x16x32_bf16(
                        pa[i], vb[j], Oa[i][j], 0, 0, 0);
        }
    }

    // ---- epilogue: O /= l, write attn_vec (i,b, n*64+d) bf16 ----
    #pragma unroll
    for (int i = 0; i < 4; ++i) {
        #pragma unroll
        for (int r = 0; r < 4; ++r) {
            int gi = i0 + wm * 64 + i * 16 + fq * 4 + r;
            float inv = 1.0f / l_st[i][r];
            #pragma unroll
            for (int j = 0; j < 2; ++j) {
                int col = n * 64 + wn * 32 + j * 16 + fr;
                attnv[((long)gi * 4 + b) * 1024 + col] = f2bf(Oa[i][j][r] * inv);
            }
        }
    }
}

// ---------------------------------------------------------------------------

__device__ __forceinline__ float blk_sum(float v, float* smv) {
    #pragma unroll
    for (int m = 32; m; m >>= 1) v += __shfl_xor(v, m, 64);
    int lane = threadIdx.x & 63, w = threadIdx.x >> 6;
    if (lane == 0) smv[w] = v;
    __syncthreads();
    v = smv[0] + smv[1] + smv[2] + smv[3];
    __syncthreads();
    return v;
}

__device__ __forceinline__ float blk_max(float v, float* smv) {
    #pragma unroll
    for (int m = 32; m; m >>= 1) v = fmaxf(v, __shfl_xor(v, m, 64));
    int lane = threadIdx.x & 63, w = threadIdx.x >> 6;
    if (lane == 0) smv[w] = v;
    __syncthreads();
    v = fmaxf(fmaxf(smv[0], smv[1]), fmaxf(smv[2], smv[3]));
    __syncthreads();
    return v;
}

__global__ __launch_bounds__(256)
void f2b_kernel(const float* __restrict__ in, u16* __restrict__ out, int n4)
{
    int i = blockIdx.x * 256 + threadIdx.x;
    if (i >= n4) return;
    float4 v = ((const float4*)in)[i];
    uint2 o;
    o.x = (unsigned)f2bf(v.x) | ((unsigned)f2bf(v.y) << 16);
    o.y = (unsigned)f2bf(v.z) | ((unsigned)f2bf(v.w) << 16);
    ((uint2*)out)[i] = o;
}

__global__ __launch_bounds__(256)
void cat_kernel(const float* __restrict__ memsl, const float* __restrict__ h,
                u16* __restrict__ cat)
{
    int i = blockIdx.x * 256 + threadIdx.x;
    float4 v = (i < 524288) ? ((const float4*)memsl)[i]
                            : ((const float4*)h)[i - 524288];
    uint2 o;
    o.x = (unsigned)f2bf(v.x) | ((unsigned)f2bf(v.y) << 16);
    o.y = (unsigned)f2bf(v.z) | ((unsigned)f2bf(v.w) << 16);
    ((uint2*)cat)[i] = o;
}

__global__ __launch_bounds__(256)
void embed_kernel(const int* __restrict__ data, const float* __restrict__ emb,
                  float* __restrict__ h)
{
    long idx = (long)blockIdx.x * 256 + threadIdx.x;
    int r = (int)(idx >> 10), d = (int)(idx & 1023);
    h[idx] = emb[(long)data[r] * 1024 + d] * 32.0f;
}

__global__ __launch_bounds__(256)
void posemb_kernel(u16* __restrict__ pe)
{
    int idx = blockIdx.x * 256 + threadIdx.x;
    int p = idx >> 10, d = idx & 1023;
    float pos = (float)(1023 - p);
    int j = d & 511;
    float invf = powf(10000.0f, -(float)j * (1.0f / 512.0f));
    float a = pos * invf;
    pe[idx] = f2bf((d < 512) ? sinf(a) : cosf(a));
}

__global__ __launch_bounds__(256)
void qwqr_kernel(const u16* __restrict__ heads, const float* __restrict__ rwb,
                 const float* __restrict__ rrb, u16* __restrict__ qw,
                 u16* __restrict__ qr)
{
    int idx = blockIdx.x * 256 + threadIdx.x;
    int d = idx & 63, i = (idx >> 6) & 511, n = (idx >> 15) & 15, b = idx >> 19;
    float v = bf2f(heads[(long)((512 + i) * 4 + b) * 3072 + n * 64 + d]);
    int e = n * 64 + d;
    qw[idx] = f2bf(v + rwb[e]);
    qr[idx] = f2bf(v + rrb[e]);
}

__global__ __launch_bounds__(256)
void add_ln_kernel(float* __restrict__ h, const float* __restrict__ res,
                   const float* __restrict__ g, const float* __restrict__ be)
{
    __shared__ float smv[4];
    int row = blockIdx.x, t = threadIdx.x;
    float* hp = h + (long)row * 1024;
    float4 x = *(float4*)(hp + t * 4);
    float4 rv = *(const float4*)(res + (long)row * 1024 + t * 4);
    x.x += rv.x; x.y += rv.y; x.z += rv.z; x.w += rv.w;
    float s = blk_sum(x.x + x.y + x.z + x.w, smv);
    float mu = s * (1.0f / 1024.0f);
    float d0 = x.x - mu, d1 = x.y - mu, d2 = x.z - mu, d3 = x.w - mu;
    float s2 = blk_sum(d0 * d0 + d1 * d1 + d2 * d2 + d3 * d3, smv);
    float inv = rsqrtf(s2 * (1.0f / 1024.0f) + 1e-5f);
    float4 gg = *(const float4*)(g + t * 4);
    float4 bb = *(const float4*)(be + t * 4);
    float4 o;
    o.x = d0 * inv * gg.x + bb.x;
    o.y = d1 * inv * gg.y + bb.y;
    o.z = d2 * inv * gg.z + bb.z;
    o.w = d3 * inv * gg.w + bb.w;
    *(float4*)(hp + t * 4) = o;
}

__global__ void init_ms_kernel(float2* __restrict__ ms)
{
    int i = blockIdx.x * 256 + threadIdx.x;
    if (i < 2048) ms[i] = make_float2(-3e38f, 0.f);
}

__global__ __launch_bounds__(256)
void merge_kernel(const float* __restrict__ chunk, float2* __restrict__ ms, int CN)
{
    __shared__ float smv[4];
    int row = blockIdx.x, t = threadIdx.x;
    const float* cp = chunk + (long)row * CN;
    float m = -3e38f;
    for (int j = t; j < CN; j += 256) m = fmaxf(m, cp[j]);
    m = blk_max(m, smv);
    float s = 0.f;
    for (int j = t; j < CN; j += 256) s += __expf(cp[j] - m);
    s = blk_sum(s, smv);
    if (t == 0) {
        float2 cur = ms[row];
        float nm = fmaxf(cur.x, m);
        ms[row] = make_float2(nm, cur.y * __expf(cur.x - nm) + s * __expf(m - nm));
    }
}

__global__ __launch_bounds__(256)
void final_kernel(const float* __restrict__ h, const float* __restrict__ emb,
                  const float* __restrict__ ob, const int* __restrict__ target,
                  const float2* __restrict__ ms, float* __restrict__ out)
{
    __shared__ float smv[4];
    int row = blockIdx.x, t = threadIdx.x;
    int tok = target[row];
    const float* hp = h + (long)row * 1024;
    const float* ep = emb + (long)tok * 1024;
    float4 a = *(const float4*)(hp + t * 4);
    float4 b = *(const float4*)(ep + t * 4);
    float s = blk_sum(a.x * b.x + a.y * b.y + a.z * b.z + a.w * b.w, smv);
    if (t == 0) {
        float2 v = ms[row];
        out[row] = v.x + logf(v.y) - (s + ob[tok]);
    }
}

// ---------------------------------------------------------------------------

extern "C" void kernel_launch(void* const* d_in, const int* in_sizes, int n_in,
                              void* d_out, int out_size, void* d_ws, size_t ws_size,
                              hipStream_t stream)
{
    const int*   data     = (const int*)d_in[0];
    const int*   target   = (const int*)d_in[1];
    const float* mems     = (const float*)d_in[2];
    const float* emb      = (const float*)d_in[3];
    const float* out_bias = (const float*)d_in[4];
    const float* r_w_bias = (const float*)d_in[5];
    const float* r_r_bias = (const float*)d_in[6];
    const float* qkv_w    = (const float*)d_in[7];
    const float* r_w      = (const float*)d_in[8];
    const float* o_w      = (const float*)d_in[9];
    const float* ln1_g    = (const float*)d_in[10];
    const float* ln1_b    = (const float*)d_in[11];
    const float* ff1_w    = (const float*)d_in[12];
    const float* ff1_b    = (const float*)d_in[13];
    const float* ff2_w    = (const float*)d_in[14];
    const float* ff2_b    = (const float*)d_in[15];
    const float* ln2_g    = (const float*)d_in[16];
    const float* ln2_b    = (const float*)d_in[17];
    float* out = (float*)d_out;
    float* ws  = (float*)d_ws;

    // workspace layout (float offsets)
    float* h       = ws;                            // 2,097,152 f
    float* tmp     = ws + 2097152;                  // 2,097,152 f
    u16*  pe_bf    = (u16*)(ws + 4194304);          // 1M bf16
    u16*  rbuf_bf  = (u16*)(ws + 4718592);          // 1M bf16
    u16*  cat_bf   = (u16*)(ws + 5242880);          // 4M bf16
    u16*  heads_bf = (u16*)(ws + 7340032);          // 12.58M bf16
    u16*  qw_bf    = (u16*)(ws + 13631488);         // 2M bf16
    u16*  qr_bf    = (u16*)(ws + 14680064);         // 2M bf16
    u16*  attnv_bf = (u16*)(ws + 15728640);         // 2M bf16
    u16*  h_bf     = (u16*)(ws + 16777216);         // 1M bf16
    u16*  wqkv     = (u16*)(ws + 17825792);         // 3.15M bf16
    u16*  wr       = wqkv + 3145728;
    u16*  wo       = wr + 1048576;
    u16*  wf1      = wo + 1048576;
    u16*  wf2      = wf1 + 4194304;                 // ends at 24641536 f
    float* big     = ws + 24641536;                 // 33,554,432 f scratch
    float2* ms     = (float2*)(ws + 58195968);      // 2048 float2
    u16*  ffh_bf   = (u16*)big;                     // 2048x4096 bf16
    float* chunk   = big;                           // 2048x8192 f
    u16*  embc_bf  = (u16*)(big + 16777216);        // 8192x1024 bf16

    embed_kernel<<<8192, 256, 0, stream>>>(data, emb, h);
    posemb_kernel<<<4096, 256, 0, stream>>>(pe_bf);

    for (int l = 0; l < 6; ++l) {
        f2b_kernel<<<3072, 256, 0, stream>>>(qkv_w + (size_t)l * 3145728, wqkv, 786432);
        f2b_kernel<<<1024, 256, 0, stream>>>(r_w + (size_t)l * 1048576, wr, 262144);
        f2b_kernel<<<1024, 256, 0, stream>>>(o_w + (size_t)l * 1048576, wo, 262144);
        f2b_kernel<<<4096, 256, 0, stream>>>(ff1_w + (size_t)l * 4194304, wf1, 1048576);
        f2b_kernel<<<4096, 256, 0, stream>>>(ff2_w + (size_t)l * 4194304, wf2, 1048576);
        cat_kernel<<<4096, 256, 0, stream>>>(mems + (size_t)l * 2097152, h, cat_bf);

        // heads = cat @ qkv^T        (4096,3072,1024)
        mg<128,128,1>(stream, cat_bf, 1024, 0, 0, LINMOD, wqkv, 1024, 0, 0, LINMOD,
                      heads_bf, 3072, 0, 0, LINMOD, nullptr, 4096, 3072, 1024, 0, 1);
        // rbuf = pos_emb @ r_w^T     (1024,1024,1024) — 64-tile: 256 blocks
        mg<64,64,1>(stream, pe_bf, 1024, 0, 0, LINMOD, wr, 1024, 0, 0, LINMOD,
                    rbuf_bf, 1024, 0, 0, LINMOD, nullptr, 1024, 1024, 1024, 0, 1);

        qwqr_kernel<<<8192, 256, 0, stream>>>(heads_bf, r_w_bias, r_r_bias, qw_bf, qr_bf);

        // fused rel-attention -> attn_vec (bf16)
        attn_kernel<<<dim3(64, 4), 256, 0, stream>>>(qw_bf, qr_bf, heads_bf,
                                                     rbuf_bf, attnv_bf);

        // attn_out = attn_vec @ o_w^T (2048,1024,1024) — 64-tile: 512 blocks
        mg<64,64,0>(stream, attnv_bf, 1024, 0, 0, LINMOD, wo, 1024, 0, 0, LINMOD,
                    tmp, 1024, 0, 0, LINMOD, nullptr, 2048, 1024, 1024, 0, 1);

        add_ln_kernel<<<2048, 256, 0, stream>>>(h, tmp, ln1_g + l * 1024, ln1_b + l * 1024);
        f2b_kernel<<<2048, 256, 0, stream>>>(h, h_bf, 524288);

        // ffh = relu(h @ ff1^T + b1)  (2048,4096,1024) — 64-tile: 2048 blocks
        mg<64,64,1>(stream, h_bf, 1024, 0, 0, LINMOD, wf1, 1024, 0, 0, LINMOD,
                    ffh_bf, 4096, 0, 0, LINMOD, ff1_b + l * 4096, 2048, 4096, 1024, 1, 1);
        // ffo = ffh @ ff2^T + b2      (2048,1024,4096) — 64-tile: 512 blocks
        mg<64,64,0>(stream, ffh_bf, 4096, 0, 0, LINMOD, wf2, 4096, 0, 0, LINMOD,
                    tmp, 1024, 0, 0, LINMOD, ff2_b + l * 1024, 2048, 1024, 4096, 0, 1);

        add_ln_kernel<<<2048, 256, 0, stream>>>(h, tmp, ln2_g + l * 1024, ln2_b + l * 1024);
    }

    f2b_kernel<<<2048, 256, 0, stream>>>(h, h_bf, 524288);
    init_ms_kernel<<<8, 256, 0, stream>>>(ms);

    const int chunkN[4] = {8192, 8192, 8192, 7424};
    long off = 0;
    for (int c = 0; c < 4; ++c) {
        int CN = chunkN[c];
        int n4 = CN * 1024 / 4;
        f2b_kernel<<<(n4 + 255) / 256, 256, 0, stream>>>(emb + off * 1024, embc_bf, n4);
        mg<128,128,0>(stream, h_bf, 1024, 0, 0, LINMOD, embc_bf, 1024, 0, 0, LINMOD,
                      chunk, CN, 0, 0, LINMOD, out_bias + off, 2048, CN, 1024, 0, 1);
        merge_kernel<<<2048, 256, 0, stream>>>(chunk, ms, CN);
        off += CN;
    }
    final_kernel<<<2048, 256, 0, stream>>>(h, emb, out_bias, target, ms, out);
}